// Round 15
// baseline (853.907 us; speedup 1.0000x reference)
//
#include <hip/hip_runtime.h>
#include <hip/hip_bf16.h>
#include <stdint.h>

#define VOCAB 50000
#define EMB   128
#define HID   256
#define G4    1024   // 4*HID, gate order i,f,g,o
#define BATCH 256
#define SEQ   512
#define LOG2E 1.4426950408889634f

typedef __attribute__((ext_vector_type(8))) short bf16x8;
typedef __attribute__((ext_vector_type(4))) float f32x4;
typedef __attribute__((ext_vector_type(4))) int   i32x4;
typedef __attribute__((ext_vector_type(2))) unsigned u32x2;

__device__ __forceinline__ ushort f2bf(float f) {
  uint32_t u; __builtin_memcpy(&u, &f, 4);
  uint32_t r = (u + 0x7fffu + ((u >> 16) & 1u)) >> 16;  // RNE
  return (ushort)r;
}
__device__ __forceinline__ float asf(uint32_t x) {
  float f; __builtin_memcpy(&f, &x, 4);
  return f;
}
__device__ __forceinline__ float rcp(float x) { return __builtin_amdgcn_rcpf(x); }
__device__ __forceinline__ float ex2(float x) { return __builtin_amdgcn_exp2f(x); }

#define WAIT_LGKM() asm volatile("s_waitcnt lgkmcnt(0)" ::: "memory")
#define RAW_BAR()  do { __builtin_amdgcn_sched_barrier(0); \
                        __builtin_amdgcn_s_barrier(); \
                        __builtin_amdgcn_sched_barrier(0); } while (0)

// ---------------------------------------------------------------------------
// K0: one-time prep — W_ih pre-converted to bf16 scaled by LOG2E (so k_proj
// skips per-block f2bf of B), bias vector bvec = (b_ih+b_hh)*LOG2E (f32).
// ---------------------------------------------------------------------------
__global__ __launch_bounds__(256) void k_prep(
    const float* __restrict__ W_ih, const float* __restrict__ b_ih,
    const float* __restrict__ b_hh, ushort* __restrict__ Wihb,
    float* __restrict__ bvec) {
  int t = blockIdx.x * 256 + threadIdx.x;            // 0..131071
  Wihb[t] = f2bf(W_ih[t] * LOG2E);
  if (t < G4) bvec[t] = (b_ih[t] + b_hh[t]) * LOG2E;
}

// ---------------------------------------------------------------------------
// K1: proj_table[v][j*4+gate] = emb[v]@(W_ih*L2E)^T + bvec  (bf16,
// gate-interleaved, log2-prescaled). B loads now direct bf16 (no conv).
// ---------------------------------------------------------------------------
__global__ __launch_bounds__(256) void k_proj(
    const float* __restrict__ emb, const ushort* __restrict__ Wihb,
    const float* __restrict__ bvec, ushort* __restrict__ proj) {
  const int lane = threadIdx.x & 63;
  const int wv = threadIdx.x >> 6;
  const int vbase = (blockIdx.x * 4 + wv) * 64;
  const int lm = lane & 15, lq = lane >> 4;
  const int nt0 = blockIdx.y * 32;

  bf16x8 A[4][4];
  #pragma unroll
  for (int mt = 0; mt < 4; ++mt) {
    int v = vbase + mt * 16 + lm;
    int vc = v < VOCAB ? v : 0;
    const float* rp = emb + (size_t)vc * EMB;
    #pragma unroll
    for (int kt = 0; kt < 4; ++kt) {
      const float* p = rp + kt * 32 + lq * 8;
      #pragma unroll
      for (int i = 0; i < 8; ++i) A[mt][kt][i] = (short)f2bf(p[i]);
    }
  }
  for (int ntl = 0; ntl < 32; ++ntl) {
    const int g = (nt0 + ntl) * 16 + lm;             // gate-major row 0..1023
    const int newcol = (g & 255) * 4 + (g >> 8);     // j*4 + gate
    bf16x8 B[4];
    #pragma unroll
    for (int kt = 0; kt < 4; ++kt)
      B[kt] = *(const bf16x8*)(Wihb + (size_t)g * EMB + kt * 32 + lq * 8);
    const float bias = bvec[g];
    #pragma unroll
    for (int mt = 0; mt < 4; ++mt) {
      f32x4 acc = {0.f, 0.f, 0.f, 0.f};
      #pragma unroll
      for (int kt = 0; kt < 4; ++kt)
        acc = __builtin_amdgcn_mfma_f32_16x16x32_bf16(A[mt][kt], B[kt], acc, 0, 0, 0);
      #pragma unroll
      for (int r = 0; r < 4; ++r) {
        int row = vbase + mt * 16 + lq * 4 + r;
        if (row < VOCAB) proj[(size_t)row * G4 + newcol] = f2bf(acc[r] + bias);
      }
    }
  }
}

// ---------------------------------------------------------------------------
// K2: quantize W_hh to i8 (scale 2032) packed for the 1-lane-per-j dot4
// kernel. Entry t in [0,16384): lane=t&63, kk=(t>>6)&15, gate=(t>>10)&3,
// wv=t>>12.  j = wv*64+lane; grow = gate*256+j; k0 = kk*16.
// 16 consecutive f32 -> i32x4 of packed i8 at W3 + t*4.
// ---------------------------------------------------------------------------
__global__ __launch_bounds__(256) void k_w3(const float* __restrict__ Whh,
                                            int* __restrict__ W3) {
  const int t = blockIdx.x * 256 + threadIdx.x;      // 0..16383
  const int lane = t & 63, kk = (t >> 6) & 15, gate = (t >> 10) & 3, wv = t >> 12;
  const int grow = gate * 256 + wv * 64 + lane;
  const int k0 = kk * 16;
  const float* src = Whh + (size_t)grow * HID + k0;
  unsigned d[4];
  #pragma unroll
  for (int e = 0; e < 4; ++e) {
    unsigned acc = 0;
    #pragma unroll
    for (int b = 0; b < 4; ++b) {
      int q = (int)rintf(src[e * 4 + b] * 2032.f);
      q = q > 127 ? 127 : (q < -127 ? -127 : q);
      acc |= ((unsigned)q & 0xffu) << (8 * b);
    }
    d[e] = acc;
  }
  i32x4 o = {(int)d[0], (int)d[1], (int)d[2], (int)d[3]};
  *(i32x4*)(W3 + (size_t)t * 4) = o;
}

// ---------------------------------------------------------------------------
// K3: pure-VALU LSTM — 256 blocks x 256 THREADS (4 waves = 1 wave/SIMD ->
// ~450-VGPR no-spill budget; the r12-r14 AGPR-parking pathology had no room
// at 2 waves/SIMD). Lane j = tid owns ONE hidden col: all 4 gates local
// (256 dot4 vs 256 VGPR-pinned weight dwords), no bperm/shfl redistribution,
// h-row reads wave-uniform (broadcast = free). h: 256B LDS row ping-pong.
// ---------------------------------------------------------------------------
__global__ __launch_bounds__(256, 1) void k_lstm(
    const int* __restrict__ x, const ushort* __restrict__ proj,
    const int* __restrict__ W3, const float* __restrict__ W_fc,
    const float* __restrict__ b_fc, float* __restrict__ out) {
  __shared__ __align__(16) char hbuf[2][256];        // i8 h row, ping-pong
  __shared__ __align__(16) int xlds[SEQ];            // this row's token ids
  __shared__ float red[4];

  const int tid = threadIdx.x;                       // = hidden col j
  const int lane = tid & 63, wv = tid >> 6;          // 4 waves
  const int b0 = blockIdx.x;                         // ONE batch row per block
  const unsigned colb = (unsigned)tid * 8u;          // proj byte off (4 gates)

  // --- weight residency: 4 gates x 16 chunks = 256 VGPRs/lane, pinned ---
  i32x4 Wd[4][16];
  {
    const i32x4* wb = (const i32x4*)W3;
    #pragma unroll
    for (int gate = 0; gate < 4; ++gate)
      #pragma unroll
      for (int kk = 0; kk < 16; ++kk)
        Wd[gate][kk] = wb[(size_t)(((wv * 4 + gate) * 16) + kk) * 64 + lane];
    #pragma unroll
    for (int gate = 0; gate < 4; ++gate)
      #pragma unroll
      for (int kk = 0; kk < 16; ++kk)
        asm volatile("" : "+v"(Wd[gate][kk]));
  }

  for (int i = tid; i < SEQ; i += 256) xlds[i] = x[b0 * SEQ + i];
  if (tid < 128) ((int*)hbuf)[tid] = 0;              // both 256B buffers

  float c = 0.f, hl = 0.f;
  __syncthreads();

  const char* projb = (const char*)proj;
  u32x2 xp0, xp1;                                    // 2-step prefetch
  xp0 = *(const u32x2*)(projb + (unsigned)xlds[0] * 2048u + colb);
  xp1 = *(const u32x2*)(projb + (unsigned)xlds[1] * 2048u + colb);

  const float S2 = LOG2E / 258064.f;                 // 2032*127 dequant, log2

#define STEP(T, RB, WB, XP)                                                   \
  {                                                                           \
    i32x4 hq[16];                                    /* full h row, bcast */  \
    _Pragma("unroll")                                                         \
    for (int kk = 0; kk < 16; ++kk)                                           \
      hq[kk] = *(const i32x4*)(hbuf[RB] + kk * 16);                           \
    int ai = 0, af = 0, ag = 0, ao = 0;              /* 4 dep chains */       \
    _Pragma("unroll")                                                         \
    for (int kk = 0; kk < 16; ++kk) {                                         \
      _Pragma("unroll")                                                       \
      for (int e = 0; e < 4; ++e) {                                           \
        ai = __builtin_amdgcn_sdot4(hq[kk][e], Wd[0][kk][e], ai, false);      \
        af = __builtin_amdgcn_sdot4(hq[kk][e], Wd[1][kk][e], af, false);      \
        ag = __builtin_amdgcn_sdot4(hq[kk][e], Wd[2][kk][e], ag, false);      \
        ao = __builtin_amdgcn_sdot4(hq[kk][e], Wd[3][kk][e], ao, false);      \
      }                                                                       \
    }                                                                         \
    float gi = (float)ai * S2 + asf(XP[0] << 16);                             \
    float gf = (float)af * S2 + asf(XP[0] & 0xffff0000u);                     \
    float gg = (float)ag * S2 + asf(XP[1] << 16);                             \
    float go = (float)ao * S2 + asf(XP[1] & 0xffff0000u);                     \
    float si_ = rcp(1.f + ex2(-gi));                                          \
    float sf_ = rcp(1.f + ex2(-gf));                                          \
    float eg_ = ex2(gg + gg);                                                 \
    float tg_ = (eg_ - 1.f) * rcp(eg_ + 1.f);                                 \
    float so_ = rcp(1.f + ex2(-go));                                          \
    float cn_ = sf_ * c + si_ * tg_;                                          \
    c = cn_;                                                                  \
    float e2_ = ex2(cn_ * (2.f * LOG2E));                                     \
    float tc_ = 1.f - 2.f * rcp(e2_ + 1.f);          /* tanh(c) */            \
    float h_ = so_ * tc_;                                                     \
    hl = h_;                                                                  \
    hbuf[WB][tid] = (char)(int)rintf(h_ * 127.f);                             \
    {                                                /* gather t+2 */         \
      int t2_ = ((T) + 2 < SEQ) ? (T) + 2 : SEQ - 1;                          \
      XP = *(const u32x2*)(projb + (unsigned)xlds[t2_] * 2048u + colb);       \
    }                                                                         \
    WAIT_LGKM();                                                              \
    RAW_BAR();                                                                \
  }

  STEP(0, 0, 1, xp0);                                // t=0 (h=0 -> dots=0)
  #pragma clang loop unroll(disable)
  for (int tt = 0; tt < 255; ++tt) {                 // t = 1..510 in pairs
    STEP(2 * tt + 1, 1, 0, xp1);
    STEP(2 * tt + 2, 0, 1, xp0);
  }
  STEP(511, 1, 0, xp1);                              // final step

  // --- FC + sigmoid epilogue (each lane holds hl for its j) ---
  float p = hl * W_fc[tid];
  p += __shfl_xor(p, 1);
  p += __shfl_xor(p, 2);
  p += __shfl_xor(p, 4);
  p += __shfl_xor(p, 8);
  p += __shfl_xor(p, 16);
  p += __shfl_xor(p, 32);
  if (lane == 0) red[wv] = p;
  __syncthreads();
  if (tid == 0) {
    float s = red[0] + red[1] + red[2] + red[3] + b_fc[0];
    out[b0] = rcp(1.f + ex2(-s * LOG2E));
  }
}

// ---------------------------------------------------------------------------
extern "C" void kernel_launch(void* const* d_in, const int* in_sizes, int n_in,
                              void* d_out, int out_size, void* d_ws, size_t ws_size,
                              hipStream_t stream) {
  const int*   x    = (const int*)d_in[0];
  const float* emb  = (const float*)d_in[1];
  const float* W_ih = (const float*)d_in[2];
  const float* W_hh = (const float*)d_in[3];
  const float* b_ih = (const float*)d_in[4];
  const float* b_hh = (const float*)d_in[5];
  const float* W_fc = (const float*)d_in[6];
  const float* b_fc = (const float*)d_in[7];
  float* out = (float*)d_out;

  // ws: proj 102,400,000 | W3 262,144 | Wihb 262,144 | bvec 4,096  (~98.2 MB)
  char* ws = (char*)d_ws;
  ushort* proj = (ushort*)ws;
  int*    W3   = (int*)(ws + 102400000);
  ushort* Wihb = (ushort*)(ws + 102662144);
  float*  bvec = (float*)(ws + 102924288);

  k_prep<<<dim3(512), dim3(256), 0, stream>>>(W_ih, b_ih, b_hh, Wihb, bvec);
  k_w3<<<dim3(64), dim3(256), 0, stream>>>(W_hh, W3);
  k_proj<<<dim3(196, 2), dim3(256), 0, stream>>>(emb, Wihb, bvec, proj);
  k_lstm<<<dim3(256), dim3(256), 0, stream>>>(x, proj, W3, W_fc, b_fc, out);
}

// Round 16
// 600.446 us; speedup vs baseline: 1.4221x; 1.4221x over previous
//
#include <hip/hip_runtime.h>
#include <hip/hip_bf16.h>
#include <stdint.h>

#define VOCAB 50000
#define EMB   128
#define HID   256
#define G4    1024   // 4*HID, gate order i,f,g,o
#define BATCH 256
#define SEQ   512
#define LOG2E 1.4426950408889634f

typedef __attribute__((ext_vector_type(8))) short bf16x8;
typedef __attribute__((ext_vector_type(4))) float f32x4;
typedef __attribute__((ext_vector_type(4))) int   i32x4;
typedef __attribute__((ext_vector_type(2))) unsigned u32x2;

__device__ __forceinline__ ushort f2bf(float f) {
  uint32_t u; __builtin_memcpy(&u, &f, 4);
  uint32_t r = (u + 0x7fffu + ((u >> 16) & 1u)) >> 16;  // RNE
  return (ushort)r;
}
__device__ __forceinline__ float asf(uint32_t x) {
  float f; __builtin_memcpy(&f, &x, 4);
  return f;
}
__device__ __forceinline__ float rcp(float x) { return __builtin_amdgcn_rcpf(x); }
__device__ __forceinline__ float ex2(float x) { return __builtin_amdgcn_exp2f(x); }

#define WAIT_LGKM() asm volatile("s_waitcnt lgkmcnt(0)" ::: "memory")
#define RAW_BAR()  do { __builtin_amdgcn_sched_barrier(0); \
                        __builtin_amdgcn_s_barrier(); \
                        __builtin_amdgcn_sched_barrier(0); } while (0)

// ---------------------------------------------------------------------------
// K0: one-time prep — W_ih -> bf16*LOG2E, bvec = (b_ih+b_hh)*LOG2E.
// ---------------------------------------------------------------------------
__global__ __launch_bounds__(256) void k_prep(
    const float* __restrict__ W_ih, const float* __restrict__ b_ih,
    const float* __restrict__ b_hh, ushort* __restrict__ Wihb,
    float* __restrict__ bvec) {
  int t = blockIdx.x * 256 + threadIdx.x;            // 0..131071
  Wihb[t] = f2bf(W_ih[t] * LOG2E);
  if (t < G4) bvec[t] = (b_ih[t] + b_hh[t]) * LOG2E;
}

// ---------------------------------------------------------------------------
// K1: proj_table[v][j*4+gate] = emb[v]@(W_ih*L2E)^T + bvec (bf16, gate-
// interleaved, log2-prescaled). Unchanged from r15 (passed).
// ---------------------------------------------------------------------------
__global__ __launch_bounds__(256) void k_proj(
    const float* __restrict__ emb, const ushort* __restrict__ Wihb,
    const float* __restrict__ bvec, ushort* __restrict__ proj) {
  const int lane = threadIdx.x & 63;
  const int wv = threadIdx.x >> 6;
  const int vbase = (blockIdx.x * 4 + wv) * 64;
  const int lm = lane & 15, lq = lane >> 4;
  const int nt0 = blockIdx.y * 32;

  bf16x8 A[4][4];
  #pragma unroll
  for (int mt = 0; mt < 4; ++mt) {
    int v = vbase + mt * 16 + lm;
    int vc = v < VOCAB ? v : 0;
    const float* rp = emb + (size_t)vc * EMB;
    #pragma unroll
    for (int kt = 0; kt < 4; ++kt) {
      const float* p = rp + kt * 32 + lq * 8;
      #pragma unroll
      for (int i = 0; i < 8; ++i) A[mt][kt][i] = (short)f2bf(p[i]);
    }
  }
  for (int ntl = 0; ntl < 32; ++ntl) {
    const int g = (nt0 + ntl) * 16 + lm;             // gate-major row 0..1023
    const int newcol = (g & 255) * 4 + (g >> 8);     // j*4 + gate
    bf16x8 B[4];
    #pragma unroll
    for (int kt = 0; kt < 4; ++kt)
      B[kt] = *(const bf16x8*)(Wihb + (size_t)g * EMB + kt * 32 + lq * 8);
    const float bias = bvec[g];
    #pragma unroll
    for (int mt = 0; mt < 4; ++mt) {
      f32x4 acc = {0.f, 0.f, 0.f, 0.f};
      #pragma unroll
      for (int kt = 0; kt < 4; ++kt)
        acc = __builtin_amdgcn_mfma_f32_16x16x32_bf16(A[mt][kt], B[kt], acc, 0, 0, 0);
      #pragma unroll
      for (int r = 0; r < 4; ++r) {
        int row = vbase + mt * 16 + lq * 4 + r;
        if (row < VOCAB) proj[(size_t)row * G4 + newcol] = f2bf(acc[r] + bias);
      }
    }
  }
}

// ---------------------------------------------------------------------------
// K2: MFMA-side weights (gates g,o = rows 512..1023), i8 scale 2032, in
// mfma_i32_16x16x64_i8 B-frag order (r7-verified). Entry t:
// lane=t&63, kc=(t>>6)&3, n=(t>>8)&7 (gate2=n>>2, tt=n&3), wv=(t>>11)&3.
// grow = 512 + (n>>2)*256 + wv*64 + (n&3)*16 + (lane&15); k0 = kc*64+(lane>>4)*16.
// ---------------------------------------------------------------------------
__global__ __launch_bounds__(256) void k_w2(const float* __restrict__ Whh,
                                            int* __restrict__ W2) {
  const int t = blockIdx.x * 256 + threadIdx.x;      // 0..8191
  const int lane = t & 63, kc = (t >> 6) & 3, n = (t >> 8) & 7, wv = (t >> 11) & 3;
  const int grow = 512 + (n >> 2) * 256 + wv * 64 + (n & 3) * 16 + (lane & 15);
  const int k0 = kc * 64 + (lane >> 4) * 16;
  const float* src = Whh + (size_t)grow * HID + k0;
  unsigned d[4];
  #pragma unroll
  for (int e = 0; e < 4; ++e) {
    unsigned acc = 0;
    #pragma unroll
    for (int b = 0; b < 4; ++b) {
      int q = (int)rintf(src[e * 4 + b] * 2032.f);
      q = q > 127 ? 127 : (q < -127 ? -127 : q);
      acc |= ((unsigned)q & 0xffu) << (8 * b);
    }
    d[e] = acc;
  }
  i32x4 o = {(int)d[0], (int)d[1], (int)d[2], (int)d[3]};
  *(i32x4*)(W2 + (size_t)t * 4) = o;
}

// ---------------------------------------------------------------------------
// K3w: dot4-side weights (gates i=0,f=1 = rows 0..511), i8 scale 2032.
// Entry t: lane=t&63, kk=(t>>6)&15, G=(t>>10)&1, wv=(t>>11)&3.
// j = wv*64+lane; grow = G*256 + j; k0 = kk*16 -> 16 i8 -> i32x4.
// ---------------------------------------------------------------------------
__global__ __launch_bounds__(256) void k_w3(const float* __restrict__ Whh,
                                            int* __restrict__ W3) {
  const int t = blockIdx.x * 256 + threadIdx.x;      // 0..8191
  const int lane = t & 63, kk = (t >> 6) & 15, G = (t >> 10) & 1, wv = (t >> 11) & 3;
  const int grow = G * 256 + wv * 64 + lane;
  const int k0 = kk * 16;
  const float* src = Whh + (size_t)grow * HID + k0;
  unsigned d[4];
  #pragma unroll
  for (int e = 0; e < 4; ++e) {
    unsigned acc = 0;
    #pragma unroll
    for (int b = 0; b < 4; ++b) {
      int q = (int)rintf(src[e * 4 + b] * 2032.f);
      q = q > 127 ? 127 : (q < -127 ? -127 : q);
      acc |= ((unsigned)q & 0xffu) << (8 * b);
    }
    d[e] = acc;
  }
  i32x4 o = {(int)d[0], (int)d[1], (int)d[2], (int)d[3]};
  *(i32x4*)(W3 + (size_t)t * 4) = o;
}

// ---------------------------------------------------------------------------
// K4: dual-file hybrid LSTM — 256 blocks x 256 threads (4 waves, 1/SIMD: the
// full 256-arch-VGPR budget belongs to one wave; r12-r15 showed dot4 weights
// park/spill at 2 waves/SIMD or >128 dwords). Lane = j owns all 4 gates:
// gates i,f via 128 dot4 on 128 VGPR-pinned dwords; gates g,o via 32
// MFMA/wave on 128 AGPR-resident frags (native operand file, no copies).
// Both pipes co-issue from the same wave. h: 256B LDS row, ping-pong.
// ---------------------------------------------------------------------------
__global__ __launch_bounds__(256, 1) void k_lstm(
    const int* __restrict__ x, const ushort* __restrict__ proj,
    const int* __restrict__ W2, const int* __restrict__ W3,
    const float* __restrict__ W_fc, const float* __restrict__ b_fc,
    float* __restrict__ out) {
  __shared__ __align__(16) char hbuf[2][256];        // i8 h row, ping-pong
  __shared__ __align__(16) int xlds[SEQ];            // this row's token ids
  __shared__ float red[4];

  const int tid = threadIdx.x;                       // = hidden col j
  const int lane = tid & 63, wv = tid >> 6;          // 4 waves
  const int lq = lane >> 4, lm = lane & 15;
  const int tsel = lane >> 4;                        // tile select 0..3
  const int b0 = blockIdx.x;                         // ONE batch row per block
  const int bp = lm * 4;                             // bperm src: C row0 col lm
  const unsigned colb = (unsigned)tid * 8u;          // proj byte off (4 gates)

  // --- MFMA weights (g,o): 32 frags = 128 AGPRs, native file ---
  i32x4 Wf[8][4];                                    // [n = gate2*4+tt][kc]
  {
    const i32x4* wb = (const i32x4*)W2;
    #pragma unroll
    for (int n = 0; n < 8; ++n)
      #pragma unroll
      for (int kc = 0; kc < 4; ++kc)
        Wf[n][kc] = wb[wv * 2048 + n * 256 + kc * 64 + lane];
    #pragma unroll
    for (int n = 0; n < 8; ++n)
      #pragma unroll
      for (int kc = 0; kc < 4; ++kc)
        asm volatile("" : "+a"(Wf[n][kc]));          // pin in AGPR file
  }
  // --- dot4 weights (i,f): 32 x i32x4 = 128 VGPRs, pinned ---
  i32x4 Wd[2][16];                                   // [gate][kk]
  {
    const i32x4* wb = (const i32x4*)W3;
    #pragma unroll
    for (int G = 0; G < 2; ++G)
      #pragma unroll
      for (int kk = 0; kk < 16; ++kk)
        Wd[G][kk] = wb[wv * 2048 + G * 1024 + kk * 64 + lane];
    #pragma unroll
    for (int G = 0; G < 2; ++G)
      #pragma unroll
      for (int kk = 0; kk < 16; ++kk)
        asm volatile("" : "+v"(Wd[G][kk]));          // pin in arch VGPRs
  }

  for (int i = tid; i < SEQ; i += 256) xlds[i] = x[b0 * SEQ + i];
  if (tid < 64) ((int*)hbuf[0])[tid] = 0;            // h(0) = 0

  float c = 0.f, hl = 0.f;
  __syncthreads();

  const char* projb = (const char*)proj;
  u32x2 xp0, xp1;                                    // 2-step prefetch
  xp0 = *(const u32x2*)(projb + (unsigned)xlds[0] * 2048u + colb);
  xp1 = *(const u32x2*)(projb + (unsigned)xlds[1] * 2048u + colb);

  const float S2 = LOG2E / 258064.f;                 // 2032*127 dequant, log2

#define STEP(T, RB, WB, XP)                                                   \
  {                                                                           \
    const char* hb_ = hbuf[RB];                                               \
    i32x4 A[4];                                      /* MFMA A (broadcast) */ \
    _Pragma("unroll")                                                         \
    for (int kc = 0; kc < 4; ++kc)                                            \
      A[kc] = *(const i32x4*)(hb_ + kc * 64 + lq * 16);                       \
    i32x4 hq[16];                                    /* full h row / lane */  \
    _Pragma("unroll")                                                         \
    for (int kk = 0; kk < 16; ++kk)                                           \
      hq[kk] = *(const i32x4*)(hb_ + kk * 16);                                \
    /* matrix pipe: gates g,o — this wave's 64 j-cols, 4 tiles each */        \
    i32x4 acg[4] = {{0,0,0,0},{0,0,0,0},{0,0,0,0},{0,0,0,0}};                 \
    i32x4 aco[4] = {{0,0,0,0},{0,0,0,0},{0,0,0,0},{0,0,0,0}};                 \
    _Pragma("unroll")                                                         \
    for (int kc = 0; kc < 4; ++kc) {                                          \
      _Pragma("unroll")                                                       \
      for (int tt = 0; tt < 4; ++tt) {                                        \
        acg[tt] = __builtin_amdgcn_mfma_i32_16x16x64_i8(A[kc], Wf[tt][kc], acg[tt], 0, 0, 0);     \
        aco[tt] = __builtin_amdgcn_mfma_i32_16x16x64_i8(A[kc], Wf[4 + tt][kc], aco[tt], 0, 0, 0); \
      }                                                                       \
    }                                                                         \
    /* VALU pipe: gates i,f — 128 dot4, 4 chains (fills MFMA shadow) */       \
    int pi0 = 0, pi1 = 0, pf0 = 0, pf1 = 0;                                   \
    _Pragma("unroll")                                                         \
    for (int kk = 0; kk < 16; ++kk) {                                         \
      _Pragma("unroll")                                                       \
      for (int e = 0; e < 4; ++e) {                                           \
        if (e & 1) {                                                          \
          pi1 = __builtin_amdgcn_sdot4(hq[kk][e], Wd[0][kk][e], pi1, false);  \
          pf1 = __builtin_amdgcn_sdot4(hq[kk][e], Wd[1][kk][e], pf1, false);  \
        } else {                                                              \
          pi0 = __builtin_amdgcn_sdot4(hq[kk][e], Wd[0][kk][e], pi0, false);  \
          pf0 = __builtin_amdgcn_sdot4(hq[kk][e], Wd[1][kk][e], pf0, false);  \
        }                                                                     \
      }                                                                       \
    }                                                                         \
    int ai = pi0 + pi1, af = pf0 + pf1;                                       \
    /* extract g,o: C row0 lives in lanes 0-15 reg0 of each tile */           \
    int g0 = __builtin_amdgcn_ds_bpermute(bp, acg[0][0]);                     \
    int g1 = __builtin_amdgcn_ds_bpermute(bp, acg[1][0]);                     \
    int g2 = __builtin_amdgcn_ds_bpermute(bp, acg[2][0]);                     \
    int g3 = __builtin_amdgcn_ds_bpermute(bp, acg[3][0]);                     \
    int o0 = __builtin_amdgcn_ds_bpermute(bp, aco[0][0]);                     \
    int o1 = __builtin_amdgcn_ds_bpermute(bp, aco[1][0]);                     \
    int o2 = __builtin_amdgcn_ds_bpermute(bp, aco[2][0]);                     \
    int o3 = __builtin_amdgcn_ds_bpermute(bp, aco[3][0]);                     \
    int ag = tsel == 0 ? g0 : tsel == 1 ? g1 : tsel == 2 ? g2 : g3;           \
    int ao = tsel == 0 ? o0 : tsel == 1 ? o1 : tsel == 2 ? o2 : o3;           \
    float gi = (float)ai * S2 + asf(XP[0] << 16);                             \
    float gf = (float)af * S2 + asf(XP[0] & 0xffff0000u);                     \
    float gg = (float)ag * S2 + asf(XP[1] << 16);                             \
    float go = (float)ao * S2 + asf(XP[1] & 0xffff0000u);                     \
    float si_ = rcp(1.f + ex2(-gi));                                          \
    float sf_ = rcp(1.f + ex2(-gf));                                          \
    float eg_ = ex2(gg + gg);                                                 \
    float tg_ = (eg_ - 1.f) * rcp(eg_ + 1.f);                                 \
    float so_ = rcp(1.f + ex2(-go));                                          \
    float cn_ = sf_ * c + si_ * tg_;                                          \
    c = cn_;                                                                  \
    float e2_ = ex2(cn_ * (2.f * LOG2E));                                     \
    float tc_ = 1.f - 2.f * rcp(e2_ + 1.f);          /* tanh(c) */            \
    float h_ = so_ * tc_;                                                     \
    hl = h_;                                                                  \
    hbuf[WB][tid] = (char)(int)rintf(h_ * 127.f);                             \
    {                                                /* gather t+2 */         \
      int t2_ = ((T) + 2 < SEQ) ? (T) + 2 : SEQ - 1;                          \
      XP = *(const u32x2*)(projb + (unsigned)xlds[t2_] * 2048u + colb);       \
    }                                                                         \
    WAIT_LGKM();                                                              \
    RAW_BAR();                                                                \
  }

  #pragma clang loop unroll(disable)
  for (int tt2 = 0; tt2 < 256; ++tt2) {              // t = 0..511 in pairs
    STEP(2 * tt2, 0, 1, xp0);                        // even t reads buf0
    STEP(2 * tt2 + 1, 1, 0, xp1);                    // odd t reads buf1
  }

  // --- FC + sigmoid epilogue (each lane holds hl for its j = tid) ---
  float p = hl * W_fc[tid];
  p += __shfl_xor(p, 1);
  p += __shfl_xor(p, 2);
  p += __shfl_xor(p, 4);
  p += __shfl_xor(p, 8);
  p += __shfl_xor(p, 16);
  p += __shfl_xor(p, 32);
  if (lane == 0) red[wv] = p;
  __syncthreads();
  if (tid == 0) {
    float s = red[0] + red[1] + red[2] + red[3] + b_fc[0];
    out[b0] = rcp(1.f + ex2(-s * LOG2E));
  }
}

// ---------------------------------------------------------------------------
extern "C" void kernel_launch(void* const* d_in, const int* in_sizes, int n_in,
                              void* d_out, int out_size, void* d_ws, size_t ws_size,
                              hipStream_t stream) {
  const int*   x    = (const int*)d_in[0];
  const float* emb  = (const float*)d_in[1];
  const float* W_ih = (const float*)d_in[2];
  const float* W_hh = (const float*)d_in[3];
  const float* b_ih = (const float*)d_in[4];
  const float* b_hh = (const float*)d_in[5];
  const float* W_fc = (const float*)d_in[6];
  const float* b_fc = (const float*)d_in[7];
  float* out = (float*)d_out;

  // ws: proj 102,400,000 | W2 131,072 | W3 131,072 | Wihb 262,144 | bvec 4,096
  char* ws = (char*)d_ws;
  ushort* proj = (ushort*)ws;
  int*    W2   = (int*)(ws + 102400000);
  int*    W3   = (int*)(ws + 102531072);
  ushort* Wihb = (ushort*)(ws + 102662144);
  float*  bvec = (float*)(ws + 102924288);

  k_prep<<<dim3(512), dim3(256), 0, stream>>>(W_ih, b_ih, b_hh, Wihb, bvec);
  k_w2<<<dim3(32), dim3(256), 0, stream>>>(W_hh, W2);
  k_w3<<<dim3(32), dim3(256), 0, stream>>>(W_hh, W3);
  k_proj<<<dim3(196, 2), dim3(256), 0, stream>>>(emb, Wihb, bvec, proj);
  k_lstm<<<dim3(256), dim3(256), 0, stream>>>(x, proj, W2, W3, W_fc, b_fc, out);
}